// Round 3
// baseline (559.134 us; speedup 1.0000x reference)
//
#include <hip/hip_runtime.h>
#include <math.h>

#define HW_N 65536   // H*W
#define NCH 64       // channels
#define NB 8         // batch
#define NBINS 256
#define NBAND 512    // NB*NCH

// d_ws float-offset layout
#define WS_MIN   0      // [512] band min
#define WS_MAX   512    // [512] band max
#define WS_SUM   1024   // [512] band sum
#define WS_THR   1536   // [512] band otsu thr (normalized space)
#define WS_PFG   2048   // [512] band foreground proportion
#define WS_MEANS 2560   // [512] per-band mean of normalized band
#define WS_LO    3072   // [8] low_end
#define WS_HI    3080   // [8] high_end
#define WS_W     3088   // [512] w[n][c]
#define WS_PMIN  3600   // [64] per-(i,n) min of relu'd einsum
#define WS_PMAX  3664   // [64] per-(i,n) max

// Otsu bin index from a 256-bin histogram (executed by ONE thread).
// hist: LDS float[256]; revhb: LDS float[256] scratch.
// Mirrors the reference: bc = mn + (k+0.5)*width; var12 = (w1*w2)*(m1-m2)^2;
// first-argmax via strict '>'.  Returns the argmax bin index bi;
// threshold = mn + (bi+0.5)*width.
__device__ int otsu_bin_from_hist(const float* hist, float* revhb, float mn, float width) {
    float acc = 0.f, N = 0.f;
    for (int k = NBINS - 1; k >= 0; --k) {
        float bc = mn + (k + 0.5f) * width;
        acc += hist[k] * bc;
        revhb[k] = acc;
        N += hist[k];
    }
    float w1 = 0.f, cumhb = 0.f, best = -INFINITY;
    int bi = 0;
    for (int i = 0; i < NBINS - 1; ++i) {
        float bc = mn + (i + 0.5f) * width;
        w1 += hist[i];
        cumhb += hist[i] * bc;
        float w2 = N - w1;  // exact: integer-valued floats
        float m1 = cumhb / fmaxf(w1, 1e-12f);
        float m2 = revhb[i + 1] / fmaxf(w2, 1e-12f);
        float d = m1 - m2;
        float v = (w1 * w2) * (d * d);
        if (v > best) { best = v; bi = i; }
    }
    return bi;
}

// K1: per-band min / max / sum.  grid 512, block 256.
__global__ __launch_bounds__(256) void band_stats(const float* __restrict__ x,
                                                  float* __restrict__ ws) {
    int b = blockIdx.x;
    int t = threadIdx.x;
    const float4* p = (const float4*)(x + (size_t)b * HW_N);
    float mn = INFINITY, mx = -INFINITY, sum = 0.f;
    for (int k = t; k < HW_N / 4; k += 256) {
        float4 v = p[k];
        mn = fminf(mn, fminf(fminf(v.x, v.y), fminf(v.z, v.w)));
        mx = fmaxf(mx, fmaxf(fmaxf(v.x, v.y), fmaxf(v.z, v.w)));
        sum += v.x + v.y + v.z + v.w;
    }
    for (int o = 32; o; o >>= 1) {
        mn = fminf(mn, __shfl_down(mn, o));
        mx = fmaxf(mx, __shfl_down(mx, o));
        sum += __shfl_down(sum, o);
    }
    __shared__ float smn[4], smx[4], ssm[4];
    int wave = t >> 6, lane = t & 63;
    if (lane == 0) { smn[wave] = mn; smx[wave] = mx; ssm[wave] = sum; }
    __syncthreads();
    if (t == 0) {
        mn = fminf(fminf(smn[0], smn[1]), fminf(smn[2], smn[3]));
        mx = fmaxf(fmaxf(smx[0], smx[1]), fmaxf(smx[2], smx[3]));
        sum = ssm[0] + ssm[1] + ssm[2] + ssm[3];
        ws[WS_MIN + b] = mn;
        ws[WS_MAX + b] = mx;
        ws[WS_SUM + b] = sum;
    }
}

// K2: per-image otsu over the 64 band-means + variance -> low/high ends.
// grid 8, block 64 (one wave).
__global__ __launch_bounds__(64) void image_otsu(float* __restrict__ ws) {
    int img = blockIdx.x;
    int c = threadIdx.x;
    int b = img * NCH + c;
    float mn = ws[WS_MIN + b], mx = ws[WS_MAX + b], sum = ws[WS_SUM + b];
    float rng = mx - mn;
    float m = (rng != 0.f) ? ((sum * (1.f / HW_N) - mn) / rng) : 0.f;
    ws[WS_MEANS + b] = m;

    __shared__ float marr[NCH];
    __shared__ float hist[NBINS];
    __shared__ float revhb[NBINS];
    marr[c] = m;
    float mmn = m, mmx = m, msum = m;
    for (int o = 32; o; o >>= 1) {
        mmn = fminf(mmn, __shfl_down(mmn, o));
        mmx = fmaxf(mmx, __shfl_down(mmx, o));
        msum += __shfl_down(msum, o);
    }
    mmn = __shfl(mmn, 0); mmx = __shfl(mmx, 0); msum = __shfl(msum, 0);
    float mbar = msum * (1.f / NCH);
    float d = m - mbar;
    float sq = d * d;
    for (int o = 32; o; o >>= 1) sq += __shfl_down(sq, o);
    hist[c] = 0.f; hist[c + 64] = 0.f; hist[c + 128] = 0.f; hist[c + 192] = 0.f;
    __syncthreads();
    if (c == 0) {
        float var = sq * (1.f / NCH);     // means.var() (ddof=0), named "stdev" in ref
        float rngm = mmx - mmn;
        float width = rngm * (1.f / NBINS);
        float safe_w = (width > 0.f) ? width : 1.f;
        for (int k = 0; k < NCH; ++k) {
            int idx = (int)floorf((marr[k] - mmn) / safe_w);
            idx = min(max(idx, 0), NBINS - 1);
            hist[idx] += 1.f;
        }
        int bi = otsu_bin_from_hist(hist, revhb, mmn, width);
        float thr = mmn + (bi + 0.5f) * width;
        ws[WS_LO + img] = (thr > 0.1f) ? (thr - var) : thr;
        ws[WS_HI + img] = thr + var;
    }
}

// K3: per-band otsu + foreground proportion in ONE pass.
// pfg*N = suffix_sum(hist, bi+1) + above_half[bi], exact because
// thr = (bi+0.5)*2^-8 and fn > thr  <=>  fn*256 > bi+0.5 (power-of-2 scaling
// is rounding-free), so only bin bi needs the frac>0.5 sub-count.
// grid 512, block 256.
__global__ __launch_bounds__(256) void band_otsu_pfg(const float* __restrict__ x,
                                                     float* __restrict__ ws) {
    int b = blockIdx.x;
    int t = threadIdx.x;
    float mn = ws[WS_MIN + b], mx = ws[WS_MAX + b];
    float rng = mx - mn;
    __shared__ unsigned ihist[NBINS];
    __shared__ unsigned iabove[NBINS];   // per-bin count of fn*256 > idx+0.5
    __shared__ float hist[NBINS];
    __shared__ float revhb[NBINS];
    ihist[t] = 0u;
    iabove[t] = 0u;
    __syncthreads();

    const float4* px = (const float4*)(x + (size_t)b * HW_N);
    if (rng != 0.f) {
        float inv = 1.f / rng;
        for (int k = t; k < HW_N / 4; k += 256) {
            float4 v = px[k];
            float s0 = (v.x - mn) * inv * 256.f;
            float s1 = (v.y - mn) * inv * 256.f;
            float s2 = (v.z - mn) * inv * 256.f;
            float s3 = (v.w - mn) * inv * 256.f;
            int i0 = min((int)s0, NBINS - 1);
            int i1 = min((int)s1, NBINS - 1);
            int i2 = min((int)s2, NBINS - 1);
            int i3 = min((int)s3, NBINS - 1);
            atomicAdd(&ihist[i0], 1u);
            atomicAdd(&ihist[i1], 1u);
            atomicAdd(&ihist[i2], 1u);
            atomicAdd(&ihist[i3], 1u);
            if (s0 > i0 + 0.5f) atomicAdd(&iabove[i0], 1u);
            if (s1 > i1 + 0.5f) atomicAdd(&iabove[i1], 1u);
            if (s2 > i2 + 0.5f) atomicAdd(&iabove[i2], 1u);
            if (s3 > i3 + 0.5f) atomicAdd(&iabove[i3], 1u);
        }
    } else if (t == 0) {
        ihist[0] = HW_N;   // all normalized values are exactly 0
    }
    __syncthreads();
    hist[t] = (float)ihist[t];
    __syncthreads();
    if (t == 0) {
        float width = (rng != 0.f) ? (1.f / NBINS) : 0.f;
        int bi = otsu_bin_from_hist(hist, revhb, 0.f, width);
        unsigned cnt = iabove[bi];
        for (int k = bi + 1; k < NBINS; ++k) cnt += ihist[k];
        ws[WS_THR + b] = (bi + 0.5f) * width;
        ws[WS_PFG + b] = (float)cnt / (float)HW_N;
    }
}

// K4: w[n][c] decision + init per-pair min/max slots.  grid 1, block 512.
__global__ __launch_bounds__(512) void compute_w(float* __restrict__ ws) {
    int t = threadIdx.x;           // t = n*64 + c
    int n = t >> 6;
    float m   = ws[WS_MEANS + t];
    float pfg = ws[WS_PFG + t];
    float lo  = ws[WS_LO + n];
    float hi  = ws[WS_HI + n];
    float wv = (m >= hi && pfg > 0.2f) ? -1.f
             : ((m <= lo && pfg < 0.1f) ? 1.f : 0.f);
    ws[WS_W + t] = wv;
    if (t < 64) {
        ws[WS_PMIN + t] = INFINITY;
        ws[WS_PMAX + t] = 0.f;     // relu output is >= 0
    }
}

// K5: y[i,n,p] = relu(255 * sum_c w[n,c]*fn(x[i,c,p])), track per-(i,n) min/max.
// grid 512 (64 chunks x 8 images), block 256, 4 pixels/thread.
__global__ __launch_bounds__(256) void einsum_relu(const float* __restrict__ x,
                                                   float* __restrict__ ws,
                                                   float* __restrict__ out) {
    int img = blockIdx.x >> 6;
    int chunk = blockIdx.x & 63;
    int t = threadIdx.x;
    __shared__ float wl[NB][NCH];
    __shared__ float mnl[NCH], invl[NCH];
    if (t < NCH) {
        int b = img * NCH + t;
        float mn = ws[WS_MIN + b];
        float rng = ws[WS_MAX + b] - mn;
        mnl[t] = mn;
        invl[t] = (rng != 0.f) ? (1.f / rng) : 0.f;  // rng==0 -> fn==0
    }
    ((float*)wl)[t] = ws[WS_W + t];
    ((float*)wl)[t + 256] = ws[WS_W + t + 256];
    __syncthreads();

    const float* base = x + (size_t)img * (NCH * HW_N);
    float tmin[NB], tmax[NB];
#pragma unroll
    for (int n = 0; n < NB; ++n) { tmin[n] = INFINITY; tmax[n] = -INFINITY; }

    for (int pp = 0; pp < 4; ++pp) {
        int p = chunk * 1024 + pp * 256 + t;
        float acc[NB];
#pragma unroll
        for (int n = 0; n < NB; ++n) acc[n] = 0.f;
#pragma unroll
        for (int c = 0; c < NCH; ++c) {
            float fn = (base[(size_t)c * HW_N + p] - mnl[c]) * invl[c];
#pragma unroll
            for (int n = 0; n < NB; ++n) acc[n] = fmaf(wl[n][c], fn, acc[n]);
        }
#pragma unroll
        for (int n = 0; n < NB; ++n) {
            float y = fmaxf(acc[n] * 255.f, 0.f);
            out[((size_t)(img * NB + n)) * HW_N + p] = y;
            tmin[n] = fminf(tmin[n], y);
            tmax[n] = fmaxf(tmax[n], y);
        }
    }
#pragma unroll
    for (int n = 0; n < NB; ++n) {
        for (int o = 32; o; o >>= 1) {
            tmin[n] = fminf(tmin[n], __shfl_down(tmin[n], o));
            tmax[n] = fmaxf(tmax[n], __shfl_down(tmax[n], o));
        }
    }
    if ((t & 63) == 0) {
#pragma unroll
        for (int n = 0; n < NB; ++n) {
            // nonneg floats: int ordering == float ordering
            atomicMin((int*)&ws[WS_PMIN + img * NB + n], __float_as_int(tmin[n]));
            atomicMax((int*)&ws[WS_PMAX + img * NB + n], __float_as_int(tmax[n]));
        }
    }
}

// K6: in-place per-(i,n) min-max normalize * 255.  grid 1024 (16 blocks/pair), block 256.
__global__ __launch_bounds__(256) void norm_out(float* __restrict__ out,
                                               const float* __restrict__ ws) {
    int pair = blockIdx.x >> 4;
    int t = threadIdx.x;
    float mnp = ws[WS_PMIN + pair];
    float rng = ws[WS_PMAX + pair] - mnp;
    float4* p = (float4*)out + (size_t)pair * (HW_N / 4) + (size_t)(blockIdx.x & 15) * 1024;
    if (rng != 0.f) {
#pragma unroll
        for (int k = 0; k < 4; ++k) {
            float4 v = p[k * 256 + t];
            v.x = (v.x - mnp) / rng * 255.f;
            v.y = (v.y - mnp) / rng * 255.f;
            v.z = (v.z - mnp) / rng * 255.f;
            v.w = (v.w - mnp) / rng * 255.f;
            p[k * 256 + t] = v;
        }
    } else {
        float4 z = make_float4(0.f, 0.f, 0.f, 0.f);
#pragma unroll
        for (int k = 0; k < 4; ++k) p[k * 256 + t] = z;
    }
}

extern "C" void kernel_launch(void* const* d_in, const int* in_sizes, int n_in,
                              void* d_out, int out_size, void* d_ws, size_t ws_size,
                              hipStream_t stream) {
    const float* x = (const float*)d_in[0];
    float* out = (float*)d_out;
    float* ws = (float*)d_ws;
    band_stats<<<NBAND, 256, 0, stream>>>(x, ws);
    image_otsu<<<NB, 64, 0, stream>>>(ws);
    band_otsu_pfg<<<NBAND, 256, 0, stream>>>(x, ws);
    compute_w<<<1, 512, 0, stream>>>(ws);
    einsum_relu<<<NBAND, 256, 0, stream>>>(x, ws, out);
    norm_out<<<1024, 256, 0, stream>>>(out, ws);
}

// Round 8
// 325.873 us; speedup vs baseline: 1.7158x; 1.7158x over previous
//
#include <hip/hip_runtime.h>
#include <math.h>

#define HW_N 65536   // H*W
#define NCH 64       // channels
#define NB 8         // batch
#define NBINS 256
#define NBAND 512    // NB*NCH

// d_ws float-offset layout
#define WS_MIN   0      // [512] band min
#define WS_MAX   512    // [512] band max
#define WS_SUM   1024   // [512] band sum
#define WS_PFG   2048   // [512] band foreground proportion
#define WS_MEANS 2560   // [512] per-band mean of normalized band
#define WS_LO    3072   // [8] low_end
#define WS_HI    3080   // [8] high_end
#define WS_W     3088   // [512] w[n][c]  (n*64+c)
#define WS_PMIN  3600   // [64] per-(i,n) min of relu'd einsum
#define WS_PMAX  3664   // [64] per-(i,n) max

// ---- parallel Otsu: inclusive scan of hist & hist*bc + first-argmax ----
// All threads of the block must call (internal __syncthreads). sh holds raw
// counts on entry, inclusive cumsum on exit; shb likewise for hist*bc.
// Mirrors reference: var12[i] = w1[i]*w2[i+1]*(m1[i]-m2[i+1])^2, strict '>'
// first-argmax (tree tie-break to smaller index == first occurrence).
__device__ int otsu_argmax(float* sh, float* shb, float* sv, int* si, int t) {
    for (int o = 1; o < NBINS; o <<= 1) {
        float a = 0.f, b = 0.f;
        if (t < NBINS) {
            a = sh[t]; b = shb[t];
            if (t >= o) { a += sh[t - o]; b += shb[t - o]; }
        }
        __syncthreads();
        if (t < NBINS) { sh[t] = a; shb[t] = b; }
        __syncthreads();
    }
    float N = sh[NBINS - 1], HB = shb[NBINS - 1];
    if (t < NBINS) {
        float v = -INFINITY;
        if (t < NBINS - 1) {
            float w1 = sh[t], w2 = N - w1;       // counts: integer-exact
            float m1 = shb[t] / fmaxf(w1, 1e-12f);
            float m2 = (HB - shb[t]) / fmaxf(w2, 1e-12f);
            float d = m1 - m2;
            v = (w1 * w2) * (d * d);
        }
        sv[t] = v; si[t] = t;
    }
    __syncthreads();
    for (int o = NBINS / 2; o; o >>= 1) {
        if (t < o) {
            float vo = sv[t + o]; int io = si[t + o];
            if (vo > sv[t] || (vo == sv[t] && io < si[t])) { sv[t] = vo; si[t] = io; }
        }
        __syncthreads();
    }
    return si[0];
}

// K1: per-band min / max / sum.  grid 512, block 1024 (32 waves/CU at 2 blocks/CU).
__global__ __launch_bounds__(1024) void band_stats(const float* __restrict__ x,
                                                   float* __restrict__ ws) {
    int b = blockIdx.x;
    int t = threadIdx.x;
    const float4* p = (const float4*)(x + (size_t)b * HW_N);
    float mn = INFINITY, mx = -INFINITY, sum = 0.f;
#pragma unroll 4
    for (int k = t; k < HW_N / 4; k += 1024) {
        float4 v = p[k];
        mn = fminf(mn, fminf(fminf(v.x, v.y), fminf(v.z, v.w)));
        mx = fmaxf(mx, fmaxf(fmaxf(v.x, v.y), fmaxf(v.z, v.w)));
        sum += (v.x + v.y) + (v.z + v.w);
    }
    for (int o = 32; o; o >>= 1) {
        mn = fminf(mn, __shfl_down(mn, o));
        mx = fmaxf(mx, __shfl_down(mx, o));
        sum += __shfl_down(sum, o);
    }
    __shared__ float smn[16], smx[16], ssm[16];
    int wave = t >> 6, lane = t & 63;
    if (lane == 0) { smn[wave] = mn; smx[wave] = mx; ssm[wave] = sum; }
    __syncthreads();
    if (t == 0) {
        mn = smn[0]; mx = smx[0]; sum = ssm[0];
        for (int k = 1; k < 16; ++k) {
            mn = fminf(mn, smn[k]);
            mx = fmaxf(mx, smx[k]);
            sum += ssm[k];
        }
        ws[WS_MIN + b] = mn;
        ws[WS_MAX + b] = mx;
        ws[WS_SUM + b] = sum;
    }
}

// K2: per-image otsu over 64 band-means + variance -> low/high ends.
// grid 8, block 256 (wave0 handles the 64 means; 256 threads run the scan).
__global__ __launch_bounds__(256) void image_otsu(float* __restrict__ ws) {
    int img = blockIdx.x;
    int t = threadIdx.x;
    __shared__ float sh[NBINS], shb[NBINS], sv[NBINS];
    __shared__ int si[NBINS];
    __shared__ float sred[4];

    float m = 0.f;
    if (t < NCH) {
        int b = img * NCH + t;
        float mn = ws[WS_MIN + b], mx = ws[WS_MAX + b], sum = ws[WS_SUM + b];
        float rng = mx - mn;
        m = (rng != 0.f) ? ((sum * (1.f / HW_N) - mn) / rng) : 0.f;
        ws[WS_MEANS + b] = m;
    }
    if (t < 64) {   // NCH == 64 == one wave
        float mmn = m, mmx = m, msum = m;
        for (int o = 32; o; o >>= 1) {
            mmn = fminf(mmn, __shfl_down(mmn, o));
            mmx = fmaxf(mmx, __shfl_down(mmx, o));
            msum += __shfl_down(msum, o);
        }
        if (t == 0) { sred[0] = mmn; sred[1] = mmx; sred[2] = msum; }
    }
    if (t < NBINS) sh[t] = 0.f;
    __syncthreads();
    float mmn = sred[0], mmx = sred[1];
    float mbar = sred[2] * (1.f / NCH);
    if (t < 64) {
        float d = m - mbar;
        float sq = d * d;
        for (int o = 32; o; o >>= 1) sq += __shfl_down(sq, o);
        if (t == 0) sred[3] = sq * (1.f / NCH);   // means.var() (ddof=0)
    }
    float rngm = mmx - mmn;
    float width = rngm * (1.f / NBINS);
    float safe_w = (width > 0.f) ? width : 1.f;
    if (t < 64) {
        int idx = (int)floorf((m - mmn) / safe_w);
        idx = min(max(idx, 0), NBINS - 1);
        atomicAdd(&sh[idx], 1.f);
    }
    __syncthreads();
    if (t < NBINS) shb[t] = sh[t] * (mmn + (t + 0.5f) * width);
    __syncthreads();
    int bi = otsu_argmax(sh, shb, sv, si, t);
    if (t == 0) {
        float var = sred[3];
        float thr = mmn + (bi + 0.5f) * width;
        ws[WS_LO + img] = (thr > 0.1f) ? (thr - var) : thr;
        ws[WS_HI + img] = thr + var;
    }
}

// K3: per-band otsu + foreground proportion, ONE data pass.
// thr = (bi+0.5)/256 exactly; fn > thr  <=>  fn*256 > bi+0.5 (power-of-2
// scaling), so pfg*N = (N - cumsum[bi]) + above_half[bi].
// grid 512, block 1024.
__global__ __launch_bounds__(1024) void band_otsu_pfg(const float* __restrict__ x,
                                                      float* __restrict__ ws) {
    int b = blockIdx.x;
    int t = threadIdx.x;
    float mn = ws[WS_MIN + b], mx = ws[WS_MAX + b];
    float rng = mx - mn;
    __shared__ unsigned ihist[NBINS], iabove[NBINS];
    __shared__ float sh[NBINS], shb[NBINS], sv[NBINS];
    __shared__ int si[NBINS];
    if (t < NBINS) { ihist[t] = 0u; iabove[t] = 0u; }
    __syncthreads();

    const float4* px = (const float4*)(x + (size_t)b * HW_N);
    if (rng != 0.f) {
        float inv256 = 256.f / rng;
#pragma unroll 4
        for (int k = t; k < HW_N / 4; k += 1024) {
            float4 v = px[k];
            float s0 = (v.x - mn) * inv256;
            float s1 = (v.y - mn) * inv256;
            float s2 = (v.z - mn) * inv256;
            float s3 = (v.w - mn) * inv256;
            int i0 = min((int)s0, NBINS - 1);
            int i1 = min((int)s1, NBINS - 1);
            int i2 = min((int)s2, NBINS - 1);
            int i3 = min((int)s3, NBINS - 1);
            atomicAdd(&ihist[i0], 1u);
            atomicAdd(&ihist[i1], 1u);
            atomicAdd(&ihist[i2], 1u);
            atomicAdd(&ihist[i3], 1u);
            if (s0 > i0 + 0.5f) atomicAdd(&iabove[i0], 1u);
            if (s1 > i1 + 0.5f) atomicAdd(&iabove[i1], 1u);
            if (s2 > i2 + 0.5f) atomicAdd(&iabove[i2], 1u);
            if (s3 > i3 + 0.5f) atomicAdd(&iabove[i3], 1u);
        }
    } else if (t == 0) {
        ihist[0] = HW_N;   // all normalized values exactly 0
    }
    __syncthreads();
    float width = (rng != 0.f) ? (1.f / NBINS) : 0.f;
    if (t < NBINS) {
        float h = (float)ihist[t];
        sh[t] = h;
        shb[t] = h * ((t + 0.5f) * width);   // bc in normalized space (mn_f = 0)
    }
    __syncthreads();
    int bi = otsu_argmax(sh, shb, sv, si, t);
    if (t == 0) {
        float N = sh[NBINS - 1];
        float cnt = (N - sh[bi]) + (float)iabove[bi];   // integer-exact floats
        ws[WS_PFG + b] = cnt * (1.f / HW_N);
    }
}

// K4: w[n][c] decision + init per-pair min/max slots.  grid 1, block 512.
__global__ __launch_bounds__(512) void compute_w(float* __restrict__ ws) {
    int t = threadIdx.x;           // t = n*64 + c
    int n = t >> 6;
    float m   = ws[WS_MEANS + t];
    float pfg = ws[WS_PFG + t];
    float lo  = ws[WS_LO + n];
    float hi  = ws[WS_HI + n];
    float wv = (m >= hi && pfg > 0.2f) ? -1.f
             : ((m <= lo && pfg < 0.1f) ? 1.f : 0.f);
    ws[WS_W + t] = wv;
    if (t < 64) {
        ws[WS_PMIN + t] = INFINITY;
        ws[WS_PMAX + t] = 0.f;     // relu output is >= 0
    }
}

// K5: y[i,n,p] = relu(255 * sum_c w[n,c]*fn(x[i,c,p])), per-(i,n) min/max.
// float4 per thread (4 px), channel loop unrolled x4 -> 4 independent 16B
// loads in flight. grid 512 (8 img x 64 chunks), block 256.
__global__ __launch_bounds__(256, 2) void einsum_relu(const float* __restrict__ x,
                                                      float* __restrict__ ws,
                                                      float* __restrict__ out) {
    int img = blockIdx.x >> 6;
    int chunk = blockIdx.x & 63;
    int t = threadIdx.x;
    __shared__ float4 wt0[NCH], wt1[NCH];   // wt0[c]={w[0..3][c]}, wt1[c]={w[4..7][c]}
    __shared__ float2 cp[NCH];              // (mn_c, inv_c)
    if (t < NCH) {
        int b = img * NCH + t;
        float mn = ws[WS_MIN + b];
        float rng = ws[WS_MAX + b] - mn;
        cp[t] = make_float2(mn, (rng != 0.f) ? (1.f / rng) : 0.f);
        wt0[t] = make_float4(ws[WS_W + 0 * NCH + t], ws[WS_W + 1 * NCH + t],
                             ws[WS_W + 2 * NCH + t], ws[WS_W + 3 * NCH + t]);
        wt1[t] = make_float4(ws[WS_W + 4 * NCH + t], ws[WS_W + 5 * NCH + t],
                             ws[WS_W + 6 * NCH + t], ws[WS_W + 7 * NCH + t]);
    }
    __syncthreads();

    const int Q = HW_N / 4;                 // float4s per channel
    int q = chunk * 256 + t;                // this thread's pixel-quad
    const float4* px = (const float4*)x + (size_t)img * NCH * Q + q;

    float4 acc0, acc1, acc2, acc3, acc4, acc5, acc6, acc7;
    acc0 = acc1 = acc2 = acc3 = acc4 = acc5 = acc6 = acc7 = make_float4(0.f, 0.f, 0.f, 0.f);

#define PROC(v, ci)                                                            \
    {                                                                          \
        float2 pc = cp[ci];                                                    \
        float4 w0 = wt0[ci], w1 = wt1[ci];                                     \
        float fx = (v.x - pc.x) * pc.y, fy = (v.y - pc.x) * pc.y;              \
        float fz = (v.z - pc.x) * pc.y, fw = (v.w - pc.x) * pc.y;              \
        acc0.x = fmaf(w0.x, fx, acc0.x); acc0.y = fmaf(w0.x, fy, acc0.y);      \
        acc0.z = fmaf(w0.x, fz, acc0.z); acc0.w = fmaf(w0.x, fw, acc0.w);      \
        acc1.x = fmaf(w0.y, fx, acc1.x); acc1.y = fmaf(w0.y, fy, acc1.y);      \
        acc1.z = fmaf(w0.y, fz, acc1.z); acc1.w = fmaf(w0.y, fw, acc1.w);      \
        acc2.x = fmaf(w0.z, fx, acc2.x); acc2.y = fmaf(w0.z, fy, acc2.y);      \
        acc2.z = fmaf(w0.z, fz, acc2.z); acc2.w = fmaf(w0.z, fw, acc2.w);      \
        acc3.x = fmaf(w0.w, fx, acc3.x); acc3.y = fmaf(w0.w, fy, acc3.y);      \
        acc3.z = fmaf(w0.w, fz, acc3.z); acc3.w = fmaf(w0.w, fw, acc3.w);      \
        acc4.x = fmaf(w1.x, fx, acc4.x); acc4.y = fmaf(w1.x, fy, acc4.y);      \
        acc4.z = fmaf(w1.x, fz, acc4.z); acc4.w = fmaf(w1.x, fw, acc4.w);      \
        acc5.x = fmaf(w1.y, fx, acc5.x); acc5.y = fmaf(w1.y, fy, acc5.y);      \
        acc5.z = fmaf(w1.y, fz, acc5.z); acc5.w = fmaf(w1.y, fw, acc5.w);      \
        acc6.x = fmaf(w1.z, fx, acc6.x); acc6.y = fmaf(w1.z, fy, acc6.y);      \
        acc6.z = fmaf(w1.z, fz, acc6.z); acc6.w = fmaf(w1.z, fw, acc6.w);      \
        acc7.x = fmaf(w1.w, fx, acc7.x); acc7.y = fmaf(w1.w, fy, acc7.y);      \
        acc7.z = fmaf(w1.w, fz, acc7.z); acc7.w = fmaf(w1.w, fw, acc7.w);      \
    }

#pragma unroll
    for (int c = 0; c < NCH; c += 4) {
        float4 v0 = px[(size_t)(c + 0) * Q];
        float4 v1 = px[(size_t)(c + 1) * Q];
        float4 v2 = px[(size_t)(c + 2) * Q];
        float4 v3 = px[(size_t)(c + 3) * Q];
        PROC(v0, c + 0)
        PROC(v1, c + 1)
        PROC(v2, c + 2)
        PROC(v3, c + 3)
    }
#undef PROC

    float4* out4 = (float4*)out + (size_t)img * NB * Q + q;
    float tmin[NB], tmax[NB];
    float4 accs[NB] = {acc0, acc1, acc2, acc3, acc4, acc5, acc6, acc7};
#pragma unroll
    for (int n = 0; n < NB; ++n) {
        float4 a = accs[n];
        float4 y;
        y.x = fmaxf(a.x * 255.f, 0.f);
        y.y = fmaxf(a.y * 255.f, 0.f);
        y.z = fmaxf(a.z * 255.f, 0.f);
        y.w = fmaxf(a.w * 255.f, 0.f);
        out4[(size_t)n * Q] = y;
        tmin[n] = fminf(fminf(y.x, y.y), fminf(y.z, y.w));
        tmax[n] = fmaxf(fmaxf(y.x, y.y), fmaxf(y.z, y.w));
    }
#pragma unroll
    for (int n = 0; n < NB; ++n) {
        for (int o = 32; o; o >>= 1) {
            tmin[n] = fminf(tmin[n], __shfl_down(tmin[n], o));
            tmax[n] = fmaxf(tmax[n], __shfl_down(tmax[n], o));
        }
    }
    if ((t & 63) == 0) {
#pragma unroll
        for (int n = 0; n < NB; ++n) {
            // nonneg floats: int ordering == float ordering
            atomicMin((int*)&ws[WS_PMIN + img * NB + n], __float_as_int(tmin[n]));
            atomicMax((int*)&ws[WS_PMAX + img * NB + n], __float_as_int(tmax[n]));
        }
    }
}

// K6: in-place per-(i,n) min-max normalize * 255.  grid 1024, block 256.
__global__ __launch_bounds__(256) void norm_out(float* __restrict__ out,
                                                const float* __restrict__ ws) {
    int pair = blockIdx.x >> 4;
    int t = threadIdx.x;
    float mnp = ws[WS_PMIN + pair];
    float rng = ws[WS_PMAX + pair] - mnp;
    float4* p = (float4*)out + (size_t)pair * (HW_N / 4) + (size_t)(blockIdx.x & 15) * 1024;
    if (rng != 0.f) {
        float inv = 255.f / rng;
#pragma unroll
        for (int k = 0; k < 4; ++k) {
            float4 v = p[k * 256 + t];
            v.x = (v.x - mnp) * inv;
            v.y = (v.y - mnp) * inv;
            v.z = (v.z - mnp) * inv;
            v.w = (v.w - mnp) * inv;
            p[k * 256 + t] = v;
        }
    } else {
        float4 z = make_float4(0.f, 0.f, 0.f, 0.f);
#pragma unroll
        for (int k = 0; k < 4; ++k) p[k * 256 + t] = z;
    }
}

extern "C" void kernel_launch(void* const* d_in, const int* in_sizes, int n_in,
                              void* d_out, int out_size, void* d_ws, size_t ws_size,
                              hipStream_t stream) {
    const float* x = (const float*)d_in[0];
    float* out = (float*)d_out;
    float* ws = (float*)d_ws;
    band_stats<<<NBAND, 1024, 0, stream>>>(x, ws);
    image_otsu<<<NB, 256, 0, stream>>>(ws);
    band_otsu_pfg<<<NBAND, 1024, 0, stream>>>(x, ws);
    compute_w<<<1, 512, 0, stream>>>(ws);
    einsum_relu<<<NBAND, 256, 0, stream>>>(x, ws, out);
    norm_out<<<1024, 256, 0, stream>>>(out, ws);
}